// Round 6
// baseline (270.274 us; speedup 1.0000x reference)
//
#include <hip/hip_runtime.h>
#include <math.h>

#define NUM_BINS 100
#define EPS 1e-6f

// Per-block slice: [0..99] pos bins, [100..199] neg bins, [200] pos pixel count.
// Block b plain-stores its slice at ws[b*SLICE_WORDS ..] -> no ws zero-init
// kernel needed (every word overwritten), no global atomics.
#define SLICE_WORDS (2 * NUM_BINS + 1)

// LDS: 8-way replicated histogram (R8: neutral, kept — zero cost insurance).
#define NREP 8
#define SH_POSC (2 * NUM_BINS * NREP)          // 1600
#define SH_WORDS (SH_POSC + 1)                 // 1601 words = 6.4 KB

// native vector types: __builtin_nontemporal_load requires these (not HIP_vector_type)
typedef float  vfloat4 __attribute__((ext_vector_type(4)));
typedef int    vint4   __attribute__((ext_vector_type(4)));

// C=32 specialized.
// R6: all-NT loads (bypass per-CU L1 miss-tracking cap): hist 106 -> ~70us.
// R9 FAILED: launch_bounds VGPR cap -> scratch spill (WRITE_SIZE 232 MB). Reverted.
// R10: `#pragma unroll 1` bounds live range w/o cap: 265.5 -> 259.7 total. KEPT.
// R11 FAILED: f0-normal/f1-NT path split: 268.6 (slow path gates fast path). Reverted.
// R12 FAILED: XCD block swizzle: 267.8 (default dispatch's single contiguous
//   sweep window is already row-friendly; swizzle fragments it). Reverted.
// Read path conclusion: ~4.2 TB/s NT cap, flat across 8-24 outstanding/wave
//   and 16-32 waves/CU -> hard path limit (~8 B/cyc/CU return).
// R13 single change: launch structure. Drop hml_init_ws; flush per-block
//   201-word slices with plain coalesced stores (no atomics); hml_final
//   reduces the 1024 slices (823 KB, L2-resident). 3 dispatches -> 2.
//   Spill guard: hist WRITE_SIZE must stay KB-scale (~830 KB now).
__global__ __launch_bounds__(256) void hml_hist32(
    const vfloat4* __restrict__ f0v, const vfloat4* __restrict__ f1v,
    const vint4* __restrict__ gt, unsigned int* __restrict__ ws, int hw4)
{
    __shared__ unsigned int sh[SH_WORDS];
    for (int i = threadIdx.x; i < SH_WORDS; i += 256) sh[i] = 0u;
    __syncthreads();

    const int idx = blockIdx.x * 256 + threadIdx.x;
    const int col = threadIdx.x & (NREP - 1);

    vint4 g = __builtin_nontemporal_load(&gt[idx]);
    float s0 = 0.f, s1 = 0.f, s2 = 0.f, s3 = 0.f;

    #pragma unroll 1
    for (int cg = 0; cg < 32; cg += 4) {
        vfloat4 a[4], b[4];
        #pragma unroll
        for (int j = 0; j < 4; ++j)
            a[j] = __builtin_nontemporal_load(&f0v[(size_t)(cg + j) * hw4 + idx]);
        #pragma unroll
        for (int j = 0; j < 4; ++j)
            b[j] = __builtin_nontemporal_load(&f1v[(size_t)(cg + j) * hw4 + idx]);
        #pragma unroll
        for (int j = 0; j < 4; ++j) {
            float e0 = a[j].x - b[j].x + EPS;
            float e1 = a[j].y - b[j].y + EPS;
            float e2 = a[j].z - b[j].z + EPS;
            float e3 = a[j].w - b[j].w + EPS;
            s0 = fmaf(e0, e0, s0);
            s1 = fmaf(e1, e1, s1);
            s2 = fmaf(e2, e2, s2);
            s3 = fmaf(e3, e3, s3);
        }
    }

    float d[4] = { sqrtf(s0), sqrtf(s1), sqrtf(s2), sqrtf(s3) };
    int gg[4] = { g.x, g.y, g.z, g.w };

    // pos-pixel count: shfl-reduce per wave, one LDS atomic per wave
    int posc = (gg[0] == 0) + (gg[1] == 0) + (gg[2] == 0) + (gg[3] == 0);
    for (int off = 32; off > 0; off >>= 1)
        posc += __shfl_down(posc, off, 64);
    if ((threadIdx.x & 63) == 0 && posc)
        atomicAdd(&sh[SH_POSC], (unsigned)posc);

    #pragma unroll
    for (int k = 0; k < 4; ++k) {
        float dd = d[k];
        // histc: values in [0,1] only (dd>=0 from sqrt); floor(d*100) clip 99
        if (dd <= 1.0f) {
            int bin = (int)(dd * (float)NUM_BINS);
            if (bin > NUM_BINS - 1) bin = NUM_BINS - 1;
            int logical = bin + ((gg[k] != 0) ? NUM_BINS : 0);
            atomicAdd(&sh[logical * NREP + col], 1u);
        }
    }

    __syncthreads();
    // slice flush: thread i (<200) merges the 8 replicas of logical bin i and
    // plain-stores into this block's slice; thread 200 stores the pos count.
    {
        int i = threadIdx.x;
        size_t base = (size_t)blockIdx.x * SLICE_WORDS;
        if (i < 2 * NUM_BINS) {
            unsigned v = 0;
            #pragma unroll
            for (int c = 0; c < NREP; ++c) v += sh[i * NREP + c];
            ws[base + i] = v;
        } else if (i == 2 * NUM_BINS) {
            ws[base + i] = sh[SH_POSC];
        }
    }
}

// Generic fallback (any C, hw multiple of 4). Same slice scheme.
__global__ __launch_bounds__(256) void hml_hist_generic(
    const float* __restrict__ f0, const float* __restrict__ f1,
    const int* __restrict__ gt, unsigned int* __restrict__ ws,
    int hw, int C)
{
    __shared__ unsigned int sh[SLICE_WORDS];
    for (int i = threadIdx.x; i < SLICE_WORDS; i += blockDim.x) sh[i] = 0u;
    __syncthreads();

    const int hw4 = hw >> 2;
    const int idx = blockIdx.x * blockDim.x + threadIdx.x;

    if (idx < hw4) {
        const float4* __restrict__ f0v = (const float4*)f0;
        const float4* __restrict__ f1v = (const float4*)f1;
        float s0 = 0.f, s1 = 0.f, s2 = 0.f, s3 = 0.f;
        for (int c = 0; c < C; ++c) {
            float4 a = f0v[(size_t)c * hw4 + idx];
            float4 b = f1v[(size_t)c * hw4 + idx];
            float e0 = a.x - b.x + EPS, e1 = a.y - b.y + EPS;
            float e2 = a.z - b.z + EPS, e3 = a.w - b.w + EPS;
            s0 = fmaf(e0, e0, s0); s1 = fmaf(e1, e1, s1);
            s2 = fmaf(e2, e2, s2); s3 = fmaf(e3, e3, s3);
        }
        int4 g = ((const int4*)gt)[idx];
        float d[4] = { sqrtf(s0), sqrtf(s1), sqrtf(s2), sqrtf(s3) };
        int gg[4] = { g.x, g.y, g.z, g.w };
        int posc = 0;
        #pragma unroll
        for (int k = 0; k < 4; ++k) {
            posc += (gg[k] == 0) ? 1 : 0;
            float dd = d[k];
            if (dd <= 1.0f) {
                int bin = (int)(dd * (float)NUM_BINS);
                if (bin > NUM_BINS - 1) bin = NUM_BINS - 1;
                atomicAdd(&sh[bin + ((gg[k] != 0) ? NUM_BINS : 0)], 1u);
            }
        }
        if (posc) atomicAdd(&sh[2 * NUM_BINS], (unsigned)posc);
    }
    __syncthreads();
    for (int i = threadIdx.x; i < SLICE_WORDS; i += blockDim.x)
        ws[(size_t)blockIdx.x * SLICE_WORDS + i] = sh[i];
}

// Reduce nblocks slices (L2-resident, producer-consumer across dispatch
// boundary = safe), then compute the KL loss. One block, 1024 threads:
// thread t handles word (t&255) for block-range quarter (t>>8).
__global__ __launch_bounds__(1024) void hml_final(
    const unsigned int* __restrict__ ws, float* __restrict__ out,
    int hw, int nblocks)
{
    __shared__ unsigned int part[4][SLICE_WORDS];
    __shared__ float terms[NUM_BINS];
    const int t = threadIdx.x;
    const int word = t & 255;
    const int q = t >> 8;

    if (word < SLICE_WORDS) {
        unsigned acc = 0;
        #pragma unroll 4
        for (int b = q; b < nblocks; b += 4)
            acc += ws[(size_t)b * SLICE_WORDS + word];
        part[q][word] = acc;
    }
    __syncthreads();

    if (t < SLICE_WORDS)
        part[0][t] = part[0][t] + part[1][t] + part[2][t] + part[3][t];
    __syncthreads();

    unsigned pos = part[0][2 * NUM_BINS];
    float pos_size = (float)pos;
    float neg_size = (float)(hw - (int)pos);
    if (t < NUM_BINS) {
        float hp = (float)part[0][t] / pos_size;
        unsigned cn = part[0][NUM_BINS + t];
        float hn = (float)cn / neg_size;
        terms[t] = (cn > 0u) ? hn * (logf(hn) - hp) : 0.0f;
    }
    __syncthreads();
    if (t == 0) {
        float s = 0.f;
        for (int k = 0; k < NUM_BINS; ++k) s += terms[k];
        out[0] = 1.0f + s / (float)NUM_BINS;
    }
}

extern "C" void kernel_launch(void* const* d_in, const int* in_sizes, int n_in,
                              void* d_out, int out_size, void* d_ws, size_t ws_size,
                              hipStream_t stream) {
    const float* f0 = (const float*)d_in[0];
    const float* f1 = (const float*)d_in[1];
    const int*   gt = (const int*)d_in[2];
    float* out = (float*)d_out;
    unsigned int* ws = (unsigned int*)d_ws;

    const int hw = in_sizes[2];          // h*w (= 1024*1024)
    const int C  = in_sizes[0] / hw;     // channels (= 32)

    int nblocks;
    if (C == 32 && (hw & 1023) == 0) {
        const int hw4 = hw >> 2;
        nblocks = hw4 / 256;             // 1024 at 1024x1024
        hml_hist32<<<nblocks, 256, 0, stream>>>(
            (const vfloat4*)f0, (const vfloat4*)f1, (const vint4*)gt, ws, hw4);
    } else {
        const int hw4 = hw >> 2;
        nblocks = (hw4 + 255) / 256;
        hml_hist_generic<<<nblocks, 256, 0, stream>>>(f0, f1, gt, ws, hw, C);
    }

    hml_final<<<1, 1024, 0, stream>>>(ws, out, hw, nblocks);
}

// Round 9
// 263.183 us; speedup vs baseline: 1.0269x; 1.0269x over previous
//
#include <hip/hip_runtime.h>
#include <math.h>

#define NUM_BINS 100
#define EPS 1e-6f

// ws layout (uint32): [0..99] pos-bin counts, [100..199] neg-bin counts, [200] pos pixel count
#define WS_WORDS (2 * NUM_BINS + 1)

// LDS: 8-way replicated histogram (R8: neutral, kept — zero cost insurance).
#define NREP 8
#define SH_POSC (2 * NUM_BINS * NREP)          // 1600
#define SH_WORDS (SH_POSC + 1)                 // 1601 words = 6.4 KB

// native vector types: __builtin_nontemporal_load requires these (not HIP_vector_type)
typedef float  vfloat4 __attribute__((ext_vector_type(4)));
typedef int    vint4   __attribute__((ext_vector_type(4)));

__global__ void hml_init_ws(unsigned int* __restrict__ ws) {
    int i = blockIdx.x * blockDim.x + threadIdx.x;
    if (i < WS_WORDS) ws[i] = 0u;
}

// C=32 specialized.
// R6: all-NT loads (bypass per-CU L1 miss-tracking cap): hist 106 -> ~70us.
// R9 FAILED: launch_bounds VGPR cap -> scratch spill (WRITE_SIZE 232 MB). Reverted.
// R10: `#pragma unroll 1` bounds live range w/o cap: 259.7 total (BEST). KEPT.
// R11 FAILED: in-THREAD path split (f0 normal / f1 NT): 268.6 — slow path
//   gates fast path in program order. Mechanism-level hypothesis untested.
// R12 FAILED: XCD block swizzle: 267.8. Reverted.
// R13 NEUTRAL/NEG: launch fusion: 270.3. Reverted.
// R14 (3rd submit; prior two runs died in infra — rewritten without
//   template/if-constexpr as a precaution, same semantics): BLOCK-level
//   read-path split. Blocks [0, 3/8) use normal L1-allocating loads
//   (~2.6 TB/s cap), blocks [3/8, 1) use NT loads (~4.2 TB/s cap).
//   Different waves exercise the two caps concurrently, no program-order
//   coupling (fixes R11's confound). If caps add -> hist ~65 -> ~45us.
//   Spill guard: WRITE_SIZE must stay KB-scale.
__global__ __launch_bounds__(256) void hml_hist32(
    const vfloat4* __restrict__ f0v, const vfloat4* __restrict__ f1v,
    const vint4* __restrict__ gt, unsigned int* __restrict__ ws, int hw4)
{
    __shared__ unsigned int sh[SH_WORDS];
    for (int i = threadIdx.x; i < SH_WORDS; i += 256) sh[i] = 0u;
    __syncthreads();

    const int idx = blockIdx.x * 256 + threadIdx.x;
    const int col = threadIdx.x & (NREP - 1);

    vint4 g = __builtin_nontemporal_load(&gt[idx]);
    float s0 = 0.f, s1 = 0.f, s2 = 0.f, s3 = 0.f;

    // 3:5 static split balancing the ~2.6 (normal) : ~4.2 (NT) TB/s caps.
    // Wave-uniform branch (blockIdx-based), two hand-written bodies.
    if (blockIdx.x * 8u < gridDim.x * 3u) {
        // ---- normal L1-allocating loads ----
        #pragma unroll 1
        for (int cg = 0; cg < 32; cg += 4) {
            vfloat4 a[4], b[4];
            #pragma unroll
            for (int j = 0; j < 4; ++j)
                a[j] = f0v[(size_t)(cg + j) * hw4 + idx];
            #pragma unroll
            for (int j = 0; j < 4; ++j)
                b[j] = f1v[(size_t)(cg + j) * hw4 + idx];
            #pragma unroll
            for (int j = 0; j < 4; ++j) {
                float e0 = a[j].x - b[j].x + EPS;
                float e1 = a[j].y - b[j].y + EPS;
                float e2 = a[j].z - b[j].z + EPS;
                float e3 = a[j].w - b[j].w + EPS;
                s0 = fmaf(e0, e0, s0);
                s1 = fmaf(e1, e1, s1);
                s2 = fmaf(e2, e2, s2);
                s3 = fmaf(e3, e3, s3);
            }
        }
    } else {
        // ---- NT (L1-bypass) loads ----
        #pragma unroll 1
        for (int cg = 0; cg < 32; cg += 4) {
            vfloat4 a[4], b[4];
            #pragma unroll
            for (int j = 0; j < 4; ++j)
                a[j] = __builtin_nontemporal_load(&f0v[(size_t)(cg + j) * hw4 + idx]);
            #pragma unroll
            for (int j = 0; j < 4; ++j)
                b[j] = __builtin_nontemporal_load(&f1v[(size_t)(cg + j) * hw4 + idx]);
            #pragma unroll
            for (int j = 0; j < 4; ++j) {
                float e0 = a[j].x - b[j].x + EPS;
                float e1 = a[j].y - b[j].y + EPS;
                float e2 = a[j].z - b[j].z + EPS;
                float e3 = a[j].w - b[j].w + EPS;
                s0 = fmaf(e0, e0, s0);
                s1 = fmaf(e1, e1, s1);
                s2 = fmaf(e2, e2, s2);
                s3 = fmaf(e3, e3, s3);
            }
        }
    }

    float d[4] = { sqrtf(s0), sqrtf(s1), sqrtf(s2), sqrtf(s3) };
    int gg[4] = { g.x, g.y, g.z, g.w };

    // pos-pixel count: shfl-reduce per wave, one LDS atomic per wave
    int posc = (gg[0] == 0) + (gg[1] == 0) + (gg[2] == 0) + (gg[3] == 0);
    for (int off = 32; off > 0; off >>= 1)
        posc += __shfl_down(posc, off, 64);
    if ((threadIdx.x & 63) == 0 && posc)
        atomicAdd(&sh[SH_POSC], (unsigned)posc);

    #pragma unroll
    for (int k = 0; k < 4; ++k) {
        float dd = d[k];
        // histc: values in [0,1] only (dd>=0 from sqrt); floor(d*100) clip 99
        if (dd <= 1.0f) {
            int bin = (int)(dd * (float)NUM_BINS);
            if (bin > NUM_BINS - 1) bin = NUM_BINS - 1;
            int logical = bin + ((gg[k] != 0) ? NUM_BINS : 0);
            atomicAdd(&sh[logical * NREP + col], 1u);
        }
    }

    __syncthreads();
    // flush: thread i (<200) merges the 8 replicas of logical bin i, one
    // global atomic per nonzero bin; thread 200 flushes the pos count.
    {
        int i = threadIdx.x;
        if (i < 2 * NUM_BINS) {
            unsigned v = 0;
            #pragma unroll
            for (int c = 0; c < NREP; ++c) v += sh[i * NREP + c];
            if (v) atomicAdd(&ws[i], v);
        } else if (i == 2 * NUM_BINS) {
            unsigned v = sh[SH_POSC];
            if (v) atomicAdd(&ws[2 * NUM_BINS], v);
        }
    }
}

// Generic fallback (any C, hw multiple of 4).
__global__ __launch_bounds__(256) void hml_hist_generic(
    const float* __restrict__ f0, const float* __restrict__ f1,
    const int* __restrict__ gt, unsigned int* __restrict__ ws,
    int hw, int C)
{
    __shared__ unsigned int sh[WS_WORDS];
    for (int i = threadIdx.x; i < WS_WORDS; i += blockDim.x) sh[i] = 0u;
    __syncthreads();

    const int hw4 = hw >> 2;
    const int idx = blockIdx.x * blockDim.x + threadIdx.x;

    if (idx < hw4) {
        const float4* __restrict__ f0v = (const float4*)f0;
        const float4* __restrict__ f1v = (const float4*)f1;
        float s0 = 0.f, s1 = 0.f, s2 = 0.f, s3 = 0.f;
        for (int c = 0; c < C; ++c) {
            float4 a = f0v[(size_t)c * hw4 + idx];
            float4 b = f1v[(size_t)c * hw4 + idx];
            float e0 = a.x - b.x + EPS, e1 = a.y - b.y + EPS;
            float e2 = a.z - b.z + EPS, e3 = a.w - b.w + EPS;
            s0 = fmaf(e0, e0, s0); s1 = fmaf(e1, e1, s1);
            s2 = fmaf(e2, e2, s2); s3 = fmaf(e3, e3, s3);
        }
        int4 g = ((const int4*)gt)[idx];
        float d[4] = { sqrtf(s0), sqrtf(s1), sqrtf(s2), sqrtf(s3) };
        int gg[4] = { g.x, g.y, g.z, g.w };
        int posc = 0;
        #pragma unroll
        for (int k = 0; k < 4; ++k) {
            posc += (gg[k] == 0) ? 1 : 0;
            float dd = d[k];
            if (dd <= 1.0f) {
                int bin = (int)(dd * (float)NUM_BINS);
                if (bin > NUM_BINS - 1) bin = NUM_BINS - 1;
                atomicAdd(&sh[bin + ((gg[k] != 0) ? NUM_BINS : 0)], 1u);
            }
        }
        if (posc) atomicAdd(&sh[2 * NUM_BINS], (unsigned)posc);
    }
    __syncthreads();
    for (int i = threadIdx.x; i < WS_WORDS; i += blockDim.x) {
        unsigned v = sh[i];
        if (v) atomicAdd(&ws[i], v);
    }
}

__global__ void hml_final(const unsigned int* __restrict__ ws,
                          float* __restrict__ out, int hw)
{
    __shared__ float terms[NUM_BINS];
    int i = threadIdx.x;
    unsigned pos = ws[2 * NUM_BINS];
    float pos_size = (float)pos;
    float neg_size = (float)(hw - (int)pos);
    if (i < NUM_BINS) {
        float hp = (float)ws[i] / pos_size;
        unsigned cn = ws[NUM_BINS + i];
        float hn = (float)cn / neg_size;
        terms[i] = (cn > 0u) ? hn * (logf(hn) - hp) : 0.0f;
    }
    __syncthreads();
    if (i == 0) {
        float s = 0.f;
        for (int k = 0; k < NUM_BINS; ++k) s += terms[k];
        out[0] = 1.0f + s / (float)NUM_BINS;
    }
}

extern "C" void kernel_launch(void* const* d_in, const int* in_sizes, int n_in,
                              void* d_out, int out_size, void* d_ws, size_t ws_size,
                              hipStream_t stream) {
    const float* f0 = (const float*)d_in[0];
    const float* f1 = (const float*)d_in[1];
    const int*   gt = (const int*)d_in[2];
    float* out = (float*)d_out;
    unsigned int* ws = (unsigned int*)d_ws;

    const int hw = in_sizes[2];          // h*w (= 1024*1024)
    const int C  = in_sizes[0] / hw;     // channels (= 32)

    hml_init_ws<<<1, 256, 0, stream>>>(ws);

    if (C == 32 && (hw & 1023) == 0) {
        const int hw4 = hw >> 2;
        const int blocks = hw4 / 256;    // 1024 at 1024x1024
        hml_hist32<<<blocks, 256, 0, stream>>>(
            (const vfloat4*)f0, (const vfloat4*)f1, (const vint4*)gt, ws, hw4);
    } else {
        const int hw4 = hw >> 2;
        const int blocks = (hw4 + 255) / 256;
        hml_hist_generic<<<blocks, 256, 0, stream>>>(f0, f1, gt, ws, hw, C);
    }

    hml_final<<<1, 128, 0, stream>>>(ws, out, hw);
}